// Round 5
// baseline (586.312 us; speedup 1.0000x reference)
//
#include <hip/hip_runtime.h>
#include <hip/hip_fp16.h>
#include <hip/hip_cooperative_groups.h>

namespace cg = cooperative_groups;

#define N_NODES 50000
#define N_EDGES 800000
#define BSHIFT 7
#define NBKT 391                 // buckets of 128 nodes
#define CAP 3072                 // bucket capacity (mean 2047, sigma ~45)
#define TILE 2048                // edges per bin tile; NBKT*TILE >= N_EDGES
#define THREADS 512

typedef _Float16 f16x8 __attribute__((ext_vector_type(8)));
typedef float f32x4 __attribute__((ext_vector_type(4)));

__device__ __forceinline__ float edge_w(unsigned p) {
    return __half2float(__ushort_as_half((unsigned short)(p >> 16)));
}

struct SmemBin {
    unsigned pk[TILE];          // 8 KB
    unsigned short sdst[TILE];  // 4 KB
    uint2 rec[TILE];            // 16 KB bucket-sorted {pk, dst}
    int cnt[NBKT];              // histogram, then reorder cursor
    int lofs[NBKT];
    int cbase[NBKT];
    int scn[THREADS];
};                              // ~34.7 KB
struct SmemL1 {
    __align__(16) __half w2t[64][136];   // 17 KB W2^T fp16, 272B rows
    __align__(16) float w1r0[128];
    __align__(16) float w1r1[128];
    __align__(16) float b1s[128];
    float nodeA[128], nodeB[128];
};                              // ~20.4 KB
struct SmemL2 {
    float hacc[128][68];        // 34.8 KB, stride 68 (%32=4) de-conflicts banks
    float b2s[64], w3s[64];
};
struct SmemL3 {
    float nacc[128];
};
union SmemAll { SmemBin bin; SmemL1 l1; SmemL2 l2; SmemL3 l3; };  // 35.4 KB

// ---------- Phase 1: bin tile b -> LDS counting-sort reorder -> coalesced uint2 scatter ----------
__device__ void phase_bin(int b, int t, const int* __restrict__ src,
                          const int* __restrict__ dstA, const float* __restrict__ ew,
                          int* __restrict__ bcur, uint2* __restrict__ brec, SmemBin& sm) {
    int e0 = b * TILE;
    int nmax = N_EDGES - e0;
    if (nmax > TILE) nmax = TILE;
    if (nmax < 0) nmax = 0;
    if (t < NBKT) sm.cnt[t] = 0;
    __syncthreads();
    for (int i = t; i < nmax; i += THREADS) {
        int e = e0 + i;
        int d = dstA[e];
        unsigned hw = (unsigned)__half_as_ushort(__float2half(ew[e]));
        sm.pk[i] = (unsigned)src[e] | (hw << 16);
        sm.sdst[i] = (unsigned short)d;
        atomicAdd(&sm.cnt[d >> BSHIFT], 1);
    }
    __syncthreads();
    int v = (t < NBKT) ? sm.cnt[t] : 0;
    sm.scn[t] = v;
    __syncthreads();
    for (int off = 1; off < THREADS; off <<= 1) {
        int u = (t >= off) ? sm.scn[t - off] : 0;
        __syncthreads();
        sm.scn[t] += u;
        __syncthreads();
    }
    if (t < NBKT) {
        sm.lofs[t] = sm.scn[t] - v;
        sm.cbase[t] = t * CAP + (v ? atomicAdd(&bcur[t], v) : 0);
        sm.cnt[t] = 0;                     // reuse as reorder cursor
    }
    __syncthreads();
    for (int i = t; i < nmax; i += THREADS) {
        int d = sm.sdst[i];
        int bk = d >> BSHIFT;
        int pos = sm.lofs[bk] + atomicAdd(&sm.cnt[bk], 1);
        sm.rec[pos] = make_uint2(sm.pk[i], (unsigned)d);
    }
    __syncthreads();
    for (int i = t; i < nmax; i += THREADS) {
        uint2 r = sm.rec[i];
        int bk = (int)(r.y >> BSHIFT);
        brec[sm.cbase[bk] + (i - sm.lofs[bk])] = r;
    }
}

// ---------- Phase 2: edge-parallel layer-1 aggregation + MFMA 128x64x128 -> t2 fp16 ----------
__device__ void phase_l1(int b, int t, const int* __restrict__ bcur,
                         const uint2* __restrict__ brec, const float* __restrict__ x,
                         const float* __restrict__ W1, const float* __restrict__ b1,
                         const float* __restrict__ W2, __half* __restrict__ t2, SmemL1& sm) {
    int base = b * CAP;
    int n = bcur[b];
    if (n > CAP) n = CAP;                  // unreachable; safety only
    for (int idx = t; idx < 128 * 64; idx += THREADS) {
        int k = idx >> 6, nn = idx & 63;
        sm.w2t[nn][k] = __float2half(W2[idx]);
    }
    if (t < 128) {
        sm.w1r0[t] = W1[t];
        sm.w1r1[t] = W1[128 + t];
        sm.b1s[t]  = b1[t];
        sm.nodeA[t] = 0.f;
        sm.nodeB[t] = 0.f;
    }
    __syncthreads();
    for (int e = t; e < n; e += THREADS) {
        uint2 r = brec[base + e];
        float w = edge_w(r.x);
        float2 xv = ((const float2*)x)[r.x & 0xFFFF];
        int dlow = (int)(r.y & 127u);
        atomicAdd(&sm.nodeA[dlow], w * xv.x);
        atomicAdd(&sm.nodeB[dlow], w * xv.y);
    }
    __syncthreads();
    // MFMA: M=128, N=64, K=128; wave w -> rows [w*16, w*16+16)
    int wave = t >> 6, lane = t & 63;
    int m0 = wave * 16;
    int fr = lane & 15;            // A row / B col / D col
    int kb = (lane >> 4) * 8;      // same lane->k map for A and B -> permutation cancels
    float a0 = sm.nodeA[m0 + fr];
    float a1 = sm.nodeB[m0 + fr];
    f32x4 acc0 = {0.f, 0.f, 0.f, 0.f};
    f32x4 acc1 = {0.f, 0.f, 0.f, 0.f};
    f32x4 acc2 = {0.f, 0.f, 0.f, 0.f};
    f32x4 acc3 = {0.f, 0.f, 0.f, 0.f};
#pragma unroll
    for (int k0 = 0; k0 < 128; k0 += 32) {
        f16x8 av;
#pragma unroll
        for (int j = 0; j < 8; j++) {
            int k = k0 + kb + j;
            float h = fmaxf(fmaf(a0, sm.w1r0[k], fmaf(a1, sm.w1r1[k], sm.b1s[k])), 0.f);
            av[j] = (_Float16)h;
        }
        f16x8 bv0 = *(const f16x8*)&sm.w2t[ 0 + fr][k0 + kb];
        f16x8 bv1 = *(const f16x8*)&sm.w2t[16 + fr][k0 + kb];
        f16x8 bv2 = *(const f16x8*)&sm.w2t[32 + fr][k0 + kb];
        f16x8 bv3 = *(const f16x8*)&sm.w2t[48 + fr][k0 + kb];
        acc0 = __builtin_amdgcn_mfma_f32_16x16x32_f16(av, bv0, acc0, 0, 0, 0);
        acc1 = __builtin_amdgcn_mfma_f32_16x16x32_f16(av, bv1, acc1, 0, 0, 0);
        acc2 = __builtin_amdgcn_mfma_f32_16x16x32_f16(av, bv2, acc2, 0, 0, 0);
        acc3 = __builtin_amdgcn_mfma_f32_16x16x32_f16(av, bv3, acc3, 0, 0, 0);
    }
    // D layout (HW-verified): col = lane&15, row = (lane>>4)*4 + r
    int rowb = (b << BSHIFT) + m0 + (lane >> 4) * 4;
#pragma unroll
    for (int r = 0; r < 4; r++) {
        int node = rowb + r;
        if (node < N_NODES) {
            __half* o = t2 + node * 64 + fr;
            o[0]  = __float2half(acc0[r]);
            o[16] = __float2half(acc1[r]);
            o[32] = __float2half(acc2[r]);
            o[48] = __float2half(acc3[r]);
        }
    }
}

// ---------- Phase 3: edge-parallel layer-2 gather (8 lanes/edge, LDS f32 atomics) + W3 dot ----------
__device__ void phase_l2(int b, int t, const int* __restrict__ bcur,
                         const uint2* __restrict__ brec, const __half* __restrict__ t2,
                         const float* __restrict__ b2, const float* __restrict__ W3,
                         float* __restrict__ t3, SmemL2& sm) {
    int base = b * CAP;
    int n = bcur[b];
    if (n > CAP) n = CAP;
    for (int i = t; i < 128 * 68; i += THREADS) ((float*)sm.hacc)[i] = 0.f;
    if (t < 64) { sm.b2s[t] = b2[t]; sm.w3s[t] = W3[t]; }
    __syncthreads();
    int total = n * 8;
    for (int s = t; s < total; s += THREADS) {
        int e = s >> 3, fli = s & 7;
        uint2 r = brec[base + e];           // 8-lane redundant read: same line, L1 hit
        float w = edge_w(r.x);
        int dlow = (int)(r.y & 127u);
        uint4 q = *(const uint4*)(t2 + (r.x & 0xFFFF) * 64 + fli * 8);
        float* hrow = &sm.hacc[dlow][fli * 8];
        float2 f;
        f = __half22float2(*(const __half2*)&q.x);
        atomicAdd(&hrow[0], w * f.x); atomicAdd(&hrow[1], w * f.y);
        f = __half22float2(*(const __half2*)&q.y);
        atomicAdd(&hrow[2], w * f.x); atomicAdd(&hrow[3], w * f.y);
        f = __half22float2(*(const __half2*)&q.z);
        atomicAdd(&hrow[4], w * f.x); atomicAdd(&hrow[5], w * f.y);
        f = __half22float2(*(const __half2*)&q.w);
        atomicAdd(&hrow[6], w * f.x); atomicAdd(&hrow[7], w * f.y);
    }
    __syncthreads();
    // t3[node] = sum_d relu(hacc[node][d] + b2[d]) * W3[d]; 4 threads/node x 16 dims
    int nodeL = t >> 2, q4 = t & 3;
    float acc = 0.f;
    int d0 = q4 * 16;
#pragma unroll
    for (int j = 0; j < 16; j++) {
        int d = d0 + j;
        acc += fmaxf(sm.hacc[nodeL][d] + sm.b2s[d], 0.f) * sm.w3s[d];
    }
    acc += __shfl_xor(acc, 1);
    acc += __shfl_xor(acc, 2);
    int node = (b << BSHIFT) + nodeL;
    if (q4 == 0 && node < N_NODES) t3[node] = acc;
}

// ---------- Phase 4: edge-parallel layer-3 gather ----------
__device__ void phase_l3(int b, int t, const int* __restrict__ bcur,
                         const uint2* __restrict__ brec, const float* __restrict__ t3,
                         const float* __restrict__ b3, float* __restrict__ out, SmemL3& sm) {
    int base = b * CAP;
    int n = bcur[b];
    if (n > CAP) n = CAP;
    if (t < 128) sm.nacc[t] = 0.f;
    __syncthreads();
    for (int e = t; e < n; e += THREADS) {
        uint2 r = brec[base + e];
        atomicAdd(&sm.nacc[r.y & 127u], edge_w(r.x) * t3[r.x & 0xFFFF]);
    }
    __syncthreads();
    int node = (b << BSHIFT) + t;
    if (t < 128 && node < N_NODES) out[node] = sm.nacc[t] + b3[0];
}

// ===== Cooperative fused kernel: bin -> l1+MFMA -> l2+dot3 -> l3 =====
__global__ __launch_bounds__(THREADS, 4) void fused_all(
    const int* __restrict__ src, const int* __restrict__ dstA,
    const float* __restrict__ ew, const float* __restrict__ x,
    const float* __restrict__ W1, const float* __restrict__ b1,
    const float* __restrict__ W2, const float* __restrict__ b2,
    const float* __restrict__ W3, const float* __restrict__ b3,
    int* __restrict__ bcur, uint2* __restrict__ brec,
    __half* __restrict__ t2, float* __restrict__ t3, float* __restrict__ out) {
    __shared__ SmemAll sm;
    cg::grid_group grid = cg::this_grid();
    int b = blockIdx.x, t = threadIdx.x;
    phase_bin(b, t, src, dstA, ew, bcur, brec, sm.bin);
    grid.sync();
    phase_l1(b, t, bcur, brec, x, W1, b1, W2, t2, sm.l1);
    grid.sync();
    phase_l2(b, t, bcur, brec, t2, b2, W3, t3, sm.l2);
    grid.sync();
    phase_l3(b, t, bcur, brec, t3, b3, out, sm.l3);
}

// ===== Fallback: same phases as 4 plain dispatches =====
__global__ __launch_bounds__(THREADS) void k_bin(const int* src, const int* dstA, const float* ew,
                                                 int* bcur, uint2* brec) {
    __shared__ SmemBin sm;
    phase_bin(blockIdx.x, threadIdx.x, src, dstA, ew, bcur, brec, sm);
}
__global__ __launch_bounds__(THREADS) void k_l1(const int* bcur, const uint2* brec, const float* x,
                                                const float* W1, const float* b1, const float* W2,
                                                __half* t2) {
    __shared__ SmemL1 sm;
    phase_l1(blockIdx.x, threadIdx.x, bcur, brec, x, W1, b1, W2, t2, sm);
}
__global__ __launch_bounds__(THREADS) void k_l2(const int* bcur, const uint2* brec, const __half* t2,
                                                const float* b2, const float* W3, float* t3) {
    __shared__ SmemL2 sm;
    phase_l2(blockIdx.x, threadIdx.x, bcur, brec, t2, b2, W3, t3, sm);
}
__global__ __launch_bounds__(THREADS) void k_l3(const int* bcur, const uint2* brec, const float* t3,
                                                const float* b3, float* out) {
    __shared__ SmemL3 sm;
    phase_l3(blockIdx.x, threadIdx.x, bcur, brec, t3, b3, out, sm);
}

extern "C" void kernel_launch(void* const* d_in, const int* in_sizes, int n_in,
                              void* d_out, int out_size, void* d_ws, size_t ws_size,
                              hipStream_t stream) {
    const float* x  = (const float*)d_in[0];
    const int*   ei = (const int*)d_in[1];     // [2, E]
    const float* ew = (const float*)d_in[2];
    const float* W1 = (const float*)d_in[3];
    const float* b1 = (const float*)d_in[4];
    const float* W2 = (const float*)d_in[5];
    const float* b2 = (const float*)d_in[6];
    const float* W3 = (const float*)d_in[7];
    const float* b3 = (const float*)d_in[8];
    float* out = (float*)d_out;

    const int* src = ei;
    const int* dst = ei + N_EDGES;

    // workspace layout (sorted/rowspan eliminated)
    char* p = (char*)d_ws;
    int*  bcur  = (int*)p;              p += NBKT * sizeof(int);
    p = (char*)(((uintptr_t)p + 15) & ~(uintptr_t)15);
    uint2* brec = (uint2*)p;            p += (long)NBKT * CAP * sizeof(uint2);    // 9.6 MB
    __half* t2  = (__half*)p;           p += 64L * N_NODES * sizeof(__half);      // 6.4 MB
    float* t3   = (float*)p;            p += N_NODES * sizeof(float);

    hipMemsetAsync(bcur, 0, NBKT * sizeof(int), stream);

    // capture-safe occupancy guard: cooperative launch needs all 391 blocks co-resident
    static int use_coop = -1;
    if (use_coop < 0) {
        int nb = 0;
        hipError_t e = hipOccupancyMaxActiveBlocksPerMultiprocessor(&nb, fused_all, THREADS, 0);
        use_coop = (e == hipSuccess && nb * 256 >= NBKT) ? 1 : 0;
    }

    if (use_coop) {
        void* args[] = {(void*)&src, (void*)&dst, (void*)&ew, (void*)&x,
                        (void*)&W1, (void*)&b1, (void*)&W2, (void*)&b2,
                        (void*)&W3, (void*)&b3, (void*)&bcur, (void*)&brec,
                        (void*)&t2, (void*)&t3, (void*)&out};
        hipLaunchCooperativeKernel((const void*)fused_all, dim3(NBKT), dim3(THREADS),
                                   args, 0, stream);
    } else {
        k_bin<<<NBKT, THREADS, 0, stream>>>(src, dst, ew, bcur, brec);
        k_l1<<<NBKT, THREADS, 0, stream>>>(bcur, brec, x, W1, b1, W2, t2);
        k_l2<<<NBKT, THREADS, 0, stream>>>(bcur, brec, t2, b2, W3, t3);
        k_l3<<<NBKT, THREADS, 0, stream>>>(bcur, brec, t3, b3, out);
    }
}

// Round 6
// 139.469 us; speedup vs baseline: 4.2039x; 4.2039x over previous
//
#include <hip/hip_runtime.h>
#include <hip/hip_fp16.h>

#define N_NODES 50000
#define N_EDGES 800000
#define BSHIFT 7
#define NBKT 391                 // buckets of 128 nodes
#define CAP 3072                 // bucket capacity (mean 2047, sigma ~45)
#define TILE 2048                // edges per bin tile; NBKT*TILE >= N_EDGES
#define BIN_THREADS 512
#define SL_THREADS 512

typedef _Float16 f16x8 __attribute__((ext_vector_type(8)));
typedef float f32x4 __attribute__((ext_vector_type(4)));
typedef float f32x2 __attribute__((ext_vector_type(2)));

__device__ __forceinline__ float edge_w(unsigned p) {
    return __half2float(__ushort_as_half((unsigned short)(p >> 16)));
}

__device__ __forceinline__ unsigned char f32_to_fp8(float v) {
    // v_cvt_pk_fp8_f32: OCP e4m3 on gfx950, saturating
    int w = __builtin_amdgcn_cvt_pk_fp8_f32(v, v, 0, false);
    return (unsigned char)(w & 0xFF);
}

// ===== Pass 1: bin edges -> LDS counting-sort reorder -> COALESCED uint2 scatter =====
__global__ __launch_bounds__(BIN_THREADS) void bin_edges(
    const int* __restrict__ src, const int* __restrict__ dstA,
    const float* __restrict__ ew, int* __restrict__ bcur,
    uint2* __restrict__ brec) {
    __shared__ unsigned pk[TILE];          // 8 KB   src | halfw<<16
    __shared__ unsigned short sdst[TILE];  // 4 KB
    __shared__ uint2 rec[TILE];            // 16 KB  bucket-sorted {pk, dst}
    __shared__ int cnt[NBKT];              // histogram, then reorder cursor
    __shared__ int lofs[NBKT];             // local exclusive offsets
    __shared__ int cbase[NBKT];            // global run base
    __shared__ int scn[BIN_THREADS];       // scan workspace

    int t = threadIdx.x;
    int e0 = blockIdx.x * TILE;
    int nmax = N_EDGES - e0;
    if (nmax > TILE) nmax = TILE;
    if (nmax < 0) nmax = 0;
    if (t < NBKT) cnt[t] = 0;
    __syncthreads();
    for (int i = t; i < nmax; i += BIN_THREADS) {
        int e = e0 + i;
        int d = dstA[e];
        unsigned hw = (unsigned)__half_as_ushort(__float2half(ew[e]));
        pk[i] = (unsigned)src[e] | (hw << 16);
        sdst[i] = (unsigned short)d;
        atomicAdd(&cnt[d >> BSHIFT], 1);
    }
    __syncthreads();
    // 512-wide inclusive scan over bucket counts -> local exclusive offsets
    int v = (t < NBKT) ? cnt[t] : 0;
    scn[t] = v;
    __syncthreads();
    for (int off = 1; off < BIN_THREADS; off <<= 1) {
        int u = (t >= off) ? scn[t - off] : 0;
        __syncthreads();
        scn[t] += u;
        __syncthreads();
    }
    if (t < NBKT) {
        lofs[t] = scn[t] - v;
        cbase[t] = t * CAP + (v ? atomicAdd(&bcur[t], v) : 0);
        cnt[t] = 0;                        // reuse as reorder cursor
    }
    __syncthreads();
    // counting-sort reorder into LDS (bucket-major order)
    for (int i = t; i < nmax; i += BIN_THREADS) {
        int d = sdst[i];
        int bk = d >> BSHIFT;
        int pos = lofs[bk] + atomicAdd(&cnt[bk], 1);
        rec[pos] = make_uint2(pk[i], (unsigned)d);
    }
    __syncthreads();
    // coalesced scatter: consecutive i -> consecutive global addresses within each run
    for (int i = t; i < nmax; i += BIN_THREADS) {
        uint2 r = rec[i];
        int bk = (int)(r.y >> BSHIFT);
        int g = cbase[bk] + (i - lofs[bk]);
        brec[g] = r;
    }
}

// ===== Pass 2 (fused): sort bucket -> rowspan + sorted, edge-parallel layer-1 gather
//       via LDS float atomics, in-register h1 A-fragments, MFMA 128x64x128 -> t2 fp8 =====
__global__ __launch_bounds__(SL_THREADS) void sort_l1(
    const int* __restrict__ bcur, const uint2* __restrict__ brec,
    const float* __restrict__ x,
    const float* __restrict__ W1, const float* __restrict__ b1,
    const float* __restrict__ W2,
    unsigned* __restrict__ sorted, int2* __restrict__ rowspan,
    unsigned char* __restrict__ t2) {
    __shared__ unsigned spk[CAP];                    // 12 KB
    __shared__ unsigned short sdl[CAP];              // 6 KB
    __shared__ int nh[128], scn[128], lcur[128];     // 1.5 KB
    __shared__ float nodeA[128], nodeB[128];         // 1 KB
    __shared__ __align__(16) __half w2t[64][136];    // 17 KB: W2^T fp16, [n][k], 272B rows
    __shared__ __align__(16) float w1r0[128];
    __shared__ __align__(16) float w1r1[128];
    __shared__ __align__(16) float b1s[128];

    int b = blockIdx.x;
    int t = threadIdx.x;
    int base = b * CAP;
    int n = bcur[b];
    if (n > CAP) n = CAP;                // unreachable; safety only

    // stage weights
    for (int idx = t; idx < 128 * 64; idx += SL_THREADS) {
        int k = idx >> 6, nn = idx & 63;
        w2t[nn][k] = __float2half(W2[idx]);
    }
    if (t < 128) {
        w1r0[t] = W1[t];
        w1r1[t] = W1[128 + t];
        b1s[t]  = b1[t];
        nh[t] = 0;
        lcur[t] = 0;
        nodeA[t] = 0.f;
        nodeB[t] = 0.f;
    }
    __syncthreads();

    // load bucket to LDS (coalesced uint2) + per-node histogram
    for (int e = t; e < n; e += SL_THREADS) {
        uint2 r = brec[base + e];
        spk[e] = r.x;
        int d = (int)(r.y & 127u);
        sdl[e] = (unsigned short)d;
        atomicAdd(&nh[d], 1);
    }
    __syncthreads();

    // exclusive scan over 128 node counts
    int vv = 0;
    if (t < 128) { vv = nh[t]; scn[t] = vv; }
    __syncthreads();
    for (int off = 1; off < 128; off <<= 1) {
        int u = (t < 128 && t >= off) ? scn[t - off] : 0;
        __syncthreads();
        if (t < 128) scn[t] += u;
        __syncthreads();
    }
    if (t < 128) {
        int ex = scn[t] - vv;
        int node = (b << BSHIFT) + t;
        if (node < N_NODES) rowspan[node] = make_int2(base + ex, base + ex + vv);
        nh[t] = ex;                      // reuse as scatter base
    }
    __syncthreads();

    // scatter to global sorted + edge-parallel layer-1 aggregation (LDS fp32 atomics)
    for (int e = t; e < n; e += SL_THREADS) {
        unsigned p = spk[e];
        int dlow = sdl[e];
        int pos = base + nh[dlow] + atomicAdd(&lcur[dlow], 1);
        sorted[pos] = p;
        float w = edge_w(p);
        float2 xv = ((const float2*)x)[p & 0xFFFF];
        atomicAdd(&nodeA[dlow], w * xv.x);
        atomicAdd(&nodeB[dlow], w * xv.y);
    }
    __syncthreads();

    // MFMA: M=128 nodes, N=64, K=128; wave w -> rows [w*16, w*16+16)
    int wave = t >> 6, lane = t & 63;
    int m0 = wave * 16;
    int fr = lane & 15;            // A row / B col / D col
    int kb = (lane >> 4) * 8;      // same lane->k map for A and B -> permutation cancels
    float a0 = nodeA[m0 + fr];
    float a1 = nodeB[m0 + fr];
    f32x4 acc0 = {0.f, 0.f, 0.f, 0.f};
    f32x4 acc1 = {0.f, 0.f, 0.f, 0.f};
    f32x4 acc2 = {0.f, 0.f, 0.f, 0.f};
    f32x4 acc3 = {0.f, 0.f, 0.f, 0.f};
#pragma unroll
    for (int k0 = 0; k0 < 128; k0 += 32) {
        f16x8 av;
#pragma unroll
        for (int j = 0; j < 8; j++) {
            int k = k0 + kb + j;
            float h = fmaxf(fmaf(a0, w1r0[k], fmaf(a1, w1r1[k], b1s[k])), 0.f);
            av[j] = (_Float16)h;
        }
        f16x8 bv0 = *(const f16x8*)&w2t[ 0 + fr][k0 + kb];
        f16x8 bv1 = *(const f16x8*)&w2t[16 + fr][k0 + kb];
        f16x8 bv2 = *(const f16x8*)&w2t[32 + fr][k0 + kb];
        f16x8 bv3 = *(const f16x8*)&w2t[48 + fr][k0 + kb];
        acc0 = __builtin_amdgcn_mfma_f32_16x16x32_f16(av, bv0, acc0, 0, 0, 0);
        acc1 = __builtin_amdgcn_mfma_f32_16x16x32_f16(av, bv1, acc1, 0, 0, 0);
        acc2 = __builtin_amdgcn_mfma_f32_16x16x32_f16(av, bv2, acc2, 0, 0, 0);
        acc3 = __builtin_amdgcn_mfma_f32_16x16x32_f16(av, bv3, acc3, 0, 0, 0);
    }
    // D layout (HW-verified): col = lane&15, row = (lane>>4)*4 + r
    int rowb = (b << BSHIFT) + m0 + (lane >> 4) * 4;
#pragma unroll
    for (int r = 0; r < 4; r++) {
        int node = rowb + r;
        if (node < N_NODES) {
            unsigned char* o = t2 + node * 64 + fr;
            o[0]  = f32_to_fp8(acc0[r]);
            o[16] = f32_to_fp8(acc1[r]);
            o[32] = f32_to_fp8(acc2[r]);
            o[48] = f32_to_fp8(acc3[r]);
        }
    }
}

// ====== Layer 2 gather: wave per node, fp8 t2 rows (64B), 8 lanes/edge ======
__global__ void gather2_dot3(const int2* __restrict__ rowspan, const unsigned* __restrict__ sorted,
                             const unsigned char* __restrict__ t2, const float* __restrict__ b2,
                             const float* __restrict__ W3, float* __restrict__ t3) {
    int gtid = blockIdx.x * blockDim.x + threadIdx.x;
    int node = gtid >> 6;
    int lane = threadIdx.x & 63;
    if (node >= N_NODES) return;
    int eg  = lane >> 3;
    int fli = lane & 7;
    int2 sp = rowspan[node];
    float a0 = 0.f, a1 = 0.f, a2 = 0.f, a3 = 0.f, a4 = 0.f, a5 = 0.f, a6 = 0.f, a7 = 0.f;
    int e = sp.x + eg;
    for (; e + 8 < sp.y; e += 16) {
        unsigned p0 = sorted[e];
        unsigned p1 = sorted[e + 8];
        uint2 q0 = *(const uint2*)(t2 + (p0 & 0xFFFF) * 64 + fli * 8);
        uint2 q1 = *(const uint2*)(t2 + (p1 & 0xFFFF) * 64 + fli * 8);
        float w0 = edge_w(p0), w1 = edge_w(p1);
        f32x2 f;
        f = __builtin_amdgcn_cvt_pk_f32_fp8(q0.x, false); a0 = fmaf(w0, f.x, a0); a1 = fmaf(w0, f.y, a1);
        f = __builtin_amdgcn_cvt_pk_f32_fp8(q0.x, true);  a2 = fmaf(w0, f.x, a2); a3 = fmaf(w0, f.y, a3);
        f = __builtin_amdgcn_cvt_pk_f32_fp8(q0.y, false); a4 = fmaf(w0, f.x, a4); a5 = fmaf(w0, f.y, a5);
        f = __builtin_amdgcn_cvt_pk_f32_fp8(q0.y, true);  a6 = fmaf(w0, f.x, a6); a7 = fmaf(w0, f.y, a7);
        f = __builtin_amdgcn_cvt_pk_f32_fp8(q1.x, false); a0 = fmaf(w1, f.x, a0); a1 = fmaf(w1, f.y, a1);
        f = __builtin_amdgcn_cvt_pk_f32_fp8(q1.x, true);  a2 = fmaf(w1, f.x, a2); a3 = fmaf(w1, f.y, a3);
        f = __builtin_amdgcn_cvt_pk_f32_fp8(q1.y, false); a4 = fmaf(w1, f.x, a4); a5 = fmaf(w1, f.y, a5);
        f = __builtin_amdgcn_cvt_pk_f32_fp8(q1.y, true);  a6 = fmaf(w1, f.x, a6); a7 = fmaf(w1, f.y, a7);
    }
    if (e < sp.y) {
        unsigned p = sorted[e];
        uint2 q = *(const uint2*)(t2 + (p & 0xFFFF) * 64 + fli * 8);
        float w = edge_w(p);
        f32x2 f;
        f = __builtin_amdgcn_cvt_pk_f32_fp8(q.x, false); a0 = fmaf(w, f.x, a0); a1 = fmaf(w, f.y, a1);
        f = __builtin_amdgcn_cvt_pk_f32_fp8(q.x, true);  a2 = fmaf(w, f.x, a2); a3 = fmaf(w, f.y, a3);
        f = __builtin_amdgcn_cvt_pk_f32_fp8(q.y, false); a4 = fmaf(w, f.x, a4); a5 = fmaf(w, f.y, a5);
        f = __builtin_amdgcn_cvt_pk_f32_fp8(q.y, true);  a6 = fmaf(w, f.x, a6); a7 = fmaf(w, f.y, a7);
    }
#pragma unroll
    for (int off = 8; off < 64; off <<= 1) {
        a0 += __shfl_xor(a0, off); a1 += __shfl_xor(a1, off);
        a2 += __shfl_xor(a2, off); a3 += __shfl_xor(a3, off);
        a4 += __shfl_xor(a4, off); a5 += __shfl_xor(a5, off);
        a6 += __shfl_xor(a6, off); a7 += __shfl_xor(a7, off);
    }
    float4 bA = *(const float4*)(b2 + fli * 8);
    float4 bB = *(const float4*)(b2 + fli * 8 + 4);
    float4 wA = *(const float4*)(W3 + fli * 8);
    float4 wB = *(const float4*)(W3 + fli * 8 + 4);
    float h = fmaxf(a0 + bA.x, 0.f) * wA.x + fmaxf(a1 + bA.y, 0.f) * wA.y +
              fmaxf(a2 + bA.z, 0.f) * wA.z + fmaxf(a3 + bA.w, 0.f) * wA.w +
              fmaxf(a4 + bB.x, 0.f) * wB.x + fmaxf(a5 + bB.y, 0.f) * wB.y +
              fmaxf(a6 + bB.z, 0.f) * wB.z + fmaxf(a7 + bB.w, 0.f) * wB.w;
#pragma unroll
    for (int off = 1; off < 8; off <<= 1) h += __shfl_xor(h, off);
    if (lane == 0) t3[node] = h;
}

// ====== Layer 3: gather scalar t3, 16 lanes/node (wave per 4 nodes) ======
__global__ void gather3(const int2* __restrict__ rowspan, const unsigned* __restrict__ sorted,
                        const float* __restrict__ t3, const float* __restrict__ b3,
                        float* __restrict__ out) {
    int gtid = blockIdx.x * blockDim.x + threadIdx.x;
    int wid = gtid >> 6;
    int lane = threadIdx.x & 63;
    int sub = lane >> 4;
    int sl  = lane & 15;
    int node = wid * 4 + sub;
    if (node >= N_NODES) return;
    int2 sp = rowspan[node];
    float acc = 0.f;
    for (int e = sp.x + sl; e < sp.y; e += 16) {
        unsigned p = sorted[e];
        acc = fmaf(edge_w(p), t3[p & 0xFFFF], acc);
    }
#pragma unroll
    for (int off = 1; off < 16; off <<= 1) acc += __shfl_xor(acc, off);
    if (sl == 0) out[node] = acc + b3[0];
}

extern "C" void kernel_launch(void* const* d_in, const int* in_sizes, int n_in,
                              void* d_out, int out_size, void* d_ws, size_t ws_size,
                              hipStream_t stream) {
    const float* x  = (const float*)d_in[0];
    const int*   ei = (const int*)d_in[1];     // [2, E]
    const float* ew = (const float*)d_in[2];
    const float* W1 = (const float*)d_in[3];
    const float* b1 = (const float*)d_in[4];
    const float* W2 = (const float*)d_in[5];
    const float* b2 = (const float*)d_in[6];
    const float* W3 = (const float*)d_in[7];
    const float* b3 = (const float*)d_in[8];
    float* out = (float*)d_out;

    const int* src = ei;
    const int* dst = ei + N_EDGES;

    // workspace layout
    char* p = (char*)d_ws;
    int*  bcur    = (int*)p;            p += NBKT * sizeof(int);
    p = (char*)(((uintptr_t)p + 15) & ~(uintptr_t)15);
    int2* rowspan = (int2*)p;           p += N_NODES * sizeof(int2);              // 400 KB
    uint2* brec   = (uint2*)p;          p += (long)NBKT * CAP * sizeof(uint2);    // 9.6 MB
    unsigned* sorted = (unsigned*)p;    p += (long)NBKT * CAP * sizeof(unsigned); // 4.6 MB
    unsigned char* t2 = (unsigned char*)p; p += 64L * N_NODES;                    // 3.2 MB (fp8)
    float* t3     = (float*)p;          p += N_NODES * sizeof(float);

    hipMemsetAsync(bcur, 0, NBKT * sizeof(int), stream);

    // CSR build pass 1: binning with LDS reorder -> coalesced uint2 scatter
    bin_edges<<<NBKT, BIN_THREADS, 0, stream>>>(src, dst, ew, bcur, brec);

    // Fused pass 2: per-bucket sort + layer-1 aggregation + MFMA dense 128->64 -> t2 fp8
    sort_l1<<<NBKT, SL_THREADS, 0, stream>>>(bcur, brec, x, W1, b1, W2, sorted, rowspan, t2);

    // Layer 2 gather + fused layer-3 projection
    gather2_dot3<<<(N_NODES * 64 + 255) / 256, 256, 0, stream>>>(rowspan, sorted, t2, b2, W3, t3);

    // Layer 3 (16 lanes/node)
    gather3<<<((N_NODES + 3) / 4 * 64 + 255) / 256, 256, 0, stream>>>(rowspan, sorted, t3, b3, out);
}

// Round 7
// 136.035 us; speedup vs baseline: 4.3100x; 1.0252x over previous
//
#include <hip/hip_runtime.h>
#include <hip/hip_fp16.h>

#define N_NODES 50000
#define N_EDGES 800000
#define BSHIFT 7
#define NBKT 391                 // buckets of 128 nodes
#define CAP 3072                 // bucket capacity (mean 2047, sigma ~45); == 6*512
#define TILE 2048                // edges per bin tile; NBKT*TILE >= N_EDGES
#define BIN_THREADS 512
#define SL_THREADS 512

typedef _Float16 f16x8 __attribute__((ext_vector_type(8)));
typedef float f32x4 __attribute__((ext_vector_type(4)));
typedef float f32x2 __attribute__((ext_vector_type(2)));

__device__ __forceinline__ float edge_w(unsigned p) {
    return __half2float(__ushort_as_half((unsigned short)(p >> 16)));
}

__device__ __forceinline__ unsigned char f32_to_fp8(float v) {
    // v_cvt_pk_fp8_f32: OCP e4m3 on gfx950, saturating
    int w = __builtin_amdgcn_cvt_pk_fp8_f32(v, v, 0, false);
    return (unsigned char)(w & 0xFF);
}

// ===== Pass 1: bin edges -> LDS counting-sort reorder -> COALESCED uint2 scatter =====
// scan via wave shfl (2 barriers) instead of 512-wide LDS scan (18 barriers)
__global__ __launch_bounds__(BIN_THREADS) void bin_edges(
    const int* __restrict__ src, const int* __restrict__ dstA,
    const float* __restrict__ ew, int* __restrict__ bcur,
    uint2* __restrict__ brec) {
    __shared__ unsigned pk[TILE];          // 8 KB   src | halfw<<16
    __shared__ unsigned short sdst[TILE];  // 4 KB
    __shared__ uint2 rec[TILE];            // 16 KB  bucket-sorted {pk, dst}
    __shared__ int cnt[NBKT];              // histogram, then reorder cursor
    __shared__ int lofs[NBKT];             // local exclusive offsets
    __shared__ int cbase[NBKT];            // global run base
    __shared__ int wsum[8];
    __shared__ int wpre[8];

    int t = threadIdx.x;
    int lane = t & 63, wid = t >> 6;
    int e0 = blockIdx.x * TILE;
    int nmax = N_EDGES - e0;
    if (nmax > TILE) nmax = TILE;
    if (nmax < 0) nmax = 0;
    if (t < NBKT) cnt[t] = 0;
    __syncthreads();
    for (int i = t; i < nmax; i += BIN_THREADS) {
        int e = e0 + i;
        int d = dstA[e];
        unsigned hw = (unsigned)__half_as_ushort(__float2half(ew[e]));
        pk[i] = (unsigned)src[e] | (hw << 16);
        sdst[i] = (unsigned short)d;
        atomicAdd(&cnt[d >> BSHIFT], 1);
    }
    __syncthreads();
    // wave-level inclusive scan over bucket counts
    int v = (t < NBKT) ? cnt[t] : 0;
    int s = v;
#pragma unroll
    for (int off = 1; off < 64; off <<= 1) {
        int u = __shfl_up(s, off);
        if (lane >= off) s += u;
    }
    if (lane == 63) wsum[wid] = s;
    __syncthreads();
    if (t < 8) {
        int a = 0;
        for (int i = 0; i < t; i++) a += wsum[i];
        wpre[t] = a;
    }
    __syncthreads();
    int incl = s + wpre[wid];
    if (t < NBKT) {
        lofs[t] = incl - v;
        cbase[t] = t * CAP + (v ? atomicAdd(&bcur[t], v) : 0);
        cnt[t] = 0;                        // reuse as reorder cursor
    }
    __syncthreads();
    // counting-sort reorder into LDS (bucket-major order)
    for (int i = t; i < nmax; i += BIN_THREADS) {
        int d = sdst[i];
        int bk = d >> BSHIFT;
        int pos = lofs[bk] + atomicAdd(&cnt[bk], 1);
        rec[pos] = make_uint2(pk[i], (unsigned)d);
    }
    __syncthreads();
    // coalesced scatter: consecutive i -> consecutive global addresses within each run
    for (int i = t; i < nmax; i += BIN_THREADS) {
        uint2 r = rec[i];
        int bk = (int)(r.y >> BSHIFT);
        int g = cbase[bk] + (i - lofs[bk]);
        brec[g] = r;
    }
}

// ===== Pass 2 (fused): reg-held bucket sort -> rowspan + coalesced sorted write,
//       edge-parallel layer-1 (LDS f32 atomics), in-register h1 fragments,
//       MFMA 128x64x128 -> t2 fp8 =====
__global__ __launch_bounds__(SL_THREADS) void sort_l1(
    const int* __restrict__ bcur, const uint2* __restrict__ brec,
    const float* __restrict__ x,
    const float* __restrict__ W1, const float* __restrict__ b1,
    const float* __restrict__ W2,
    unsigned* __restrict__ sorted, int2* __restrict__ rowspan,
    unsigned char* __restrict__ t2) {
    __shared__ unsigned spk[CAP];                    // 12 KB: becomes SORTED edges
    __shared__ int nh[128], lcur[128];               // 1 KB
    __shared__ float nodeA[128], nodeB[128];         // 1 KB
    __shared__ __align__(16) __half w2t[64][136];    // 17 KB: W2^T fp16, [n][k], 272B rows
    __shared__ __align__(16) float w1r0[128];
    __shared__ __align__(16) float w1r1[128];
    __shared__ __align__(16) float b1s[128];
    __shared__ int wsum2[2];

    int b = blockIdx.x;
    int t = threadIdx.x;
    int lane = t & 63, wid = t >> 6;
    int base = b * CAP;
    int n = bcur[b];
    if (n > CAP) n = CAP;                // unreachable; safety only

    // stage weights
    for (int idx = t; idx < 128 * 64; idx += SL_THREADS) {
        int k = idx >> 6, nn = idx & 63;
        w2t[nn][k] = __float2half(W2[idx]);
    }
    if (t < 128) {
        w1r0[t] = W1[t];
        w1r1[t] = W1[128 + t];
        b1s[t]  = b1[t];
        nh[t] = 0;
        lcur[t] = 0;
        nodeA[t] = 0.f;
        nodeB[t] = 0.f;
    }
    __syncthreads();

    // load bucket into REGISTERS (<=6 edges/thread, static unroll) +
    // histogram + layer-1 aggregation in the same pass
    unsigned rp[6];
    int rd[6];
#pragma unroll
    for (int i = 0; i < 6; i++) {
        int e = t + i * SL_THREADS;
        if (e < n) {
            uint2 r = brec[base + e];
            rp[i] = r.x;
            rd[i] = (int)(r.y & 127u);
            atomicAdd(&nh[rd[i]], 1);
            float w = edge_w(r.x);
            float2 xv = ((const float2*)x)[r.x & 0xFFFF];
            atomicAdd(&nodeA[rd[i]], w * xv.x);
            atomicAdd(&nodeB[rd[i]], w * xv.y);
        }
    }
    __syncthreads();

    // 128-wide exclusive scan via 2-wave shfl scan
    int v = (t < 128) ? nh[t] : 0;
    int s = v;
#pragma unroll
    for (int off = 1; off < 64; off <<= 1) {
        int u = __shfl_up(s, off);
        if (lane >= off) s += u;
    }
    if (lane == 63 && wid < 2) wsum2[wid] = s;
    __syncthreads();
    if (t < 128) {
        int incl = s + (wid ? wsum2[0] : 0);
        int ex = incl - v;
        int node = (b << BSHIFT) + t;
        if (node < N_NODES) rowspan[node] = make_int2(base + ex, base + ex + v);
        nh[t] = ex;                      // reuse as scatter base
    }
    __syncthreads();

    // scatter from registers into spk in node-sorted order
#pragma unroll
    for (int i = 0; i < 6; i++) {
        int e = t + i * SL_THREADS;
        if (e < n) {
            int pos = nh[rd[i]] + atomicAdd(&lcur[rd[i]], 1);
            spk[pos] = rp[i];
        }
    }
    __syncthreads();
    // coalesced linear write of sorted edges
    for (int e = t; e < n; e += SL_THREADS) sorted[base + e] = spk[e];

    // MFMA: M=128 nodes, N=64, K=128; wave w -> rows [w*16, w*16+16)
    int wave = t >> 6;
    int m0 = wave * 16;
    int fr = lane & 15;            // A row / B col / D col
    int kb = (lane >> 4) * 8;      // same lane->k map for A and B -> permutation cancels
    float a0 = nodeA[m0 + fr];
    float a1 = nodeB[m0 + fr];
    f32x4 acc0 = {0.f, 0.f, 0.f, 0.f};
    f32x4 acc1 = {0.f, 0.f, 0.f, 0.f};
    f32x4 acc2 = {0.f, 0.f, 0.f, 0.f};
    f32x4 acc3 = {0.f, 0.f, 0.f, 0.f};
#pragma unroll
    for (int k0 = 0; k0 < 128; k0 += 32) {
        f16x8 av;
#pragma unroll
        for (int j = 0; j < 8; j++) {
            int k = k0 + kb + j;
            float h = fmaxf(fmaf(a0, w1r0[k], fmaf(a1, w1r1[k], b1s[k])), 0.f);
            av[j] = (_Float16)h;
        }
        f16x8 bv0 = *(const f16x8*)&w2t[ 0 + fr][k0 + kb];
        f16x8 bv1 = *(const f16x8*)&w2t[16 + fr][k0 + kb];
        f16x8 bv2 = *(const f16x8*)&w2t[32 + fr][k0 + kb];
        f16x8 bv3 = *(const f16x8*)&w2t[48 + fr][k0 + kb];
        acc0 = __builtin_amdgcn_mfma_f32_16x16x32_f16(av, bv0, acc0, 0, 0, 0);
        acc1 = __builtin_amdgcn_mfma_f32_16x16x32_f16(av, bv1, acc1, 0, 0, 0);
        acc2 = __builtin_amdgcn_mfma_f32_16x16x32_f16(av, bv2, acc2, 0, 0, 0);
        acc3 = __builtin_amdgcn_mfma_f32_16x16x32_f16(av, bv3, acc3, 0, 0, 0);
    }
    // D layout (HW-verified): col = lane&15, row = (lane>>4)*4 + r
    int rowb = (b << BSHIFT) + m0 + ((lane >> 4) & 3) * 4;
#pragma unroll
    for (int r = 0; r < 4; r++) {
        int node = rowb + r;
        if (node < N_NODES) {
            unsigned char* o = t2 + node * 64 + fr;
            o[0]  = f32_to_fp8(acc0[r]);
            o[16] = f32_to_fp8(acc1[r]);
            o[32] = f32_to_fp8(acc2[r]);
            o[48] = f32_to_fp8(acc3[r]);
        }
    }
}

// ====== Layer 2 gather: wave per node, fp8 t2 rows (64B), 8 lanes/edge ======
__global__ void gather2_dot3(const int2* __restrict__ rowspan, const unsigned* __restrict__ sorted,
                             const unsigned char* __restrict__ t2, const float* __restrict__ b2,
                             const float* __restrict__ W3, float* __restrict__ t3) {
    int gtid = blockIdx.x * blockDim.x + threadIdx.x;
    int node = gtid >> 6;
    int lane = threadIdx.x & 63;
    if (node >= N_NODES) return;
    int eg  = lane >> 3;
    int fli = lane & 7;
    int2 sp = rowspan[node];
    float a0 = 0.f, a1 = 0.f, a2 = 0.f, a3 = 0.f, a4 = 0.f, a5 = 0.f, a6 = 0.f, a7 = 0.f;
    int e = sp.x + eg;
    for (; e + 8 < sp.y; e += 16) {
        unsigned p0 = sorted[e];
        unsigned p1 = sorted[e + 8];
        uint2 q0 = *(const uint2*)(t2 + (p0 & 0xFFFF) * 64 + fli * 8);
        uint2 q1 = *(const uint2*)(t2 + (p1 & 0xFFFF) * 64 + fli * 8);
        float w0 = edge_w(p0), w1 = edge_w(p1);
        f32x2 f;
        f = __builtin_amdgcn_cvt_pk_f32_fp8(q0.x, false); a0 = fmaf(w0, f.x, a0); a1 = fmaf(w0, f.y, a1);
        f = __builtin_amdgcn_cvt_pk_f32_fp8(q0.x, true);  a2 = fmaf(w0, f.x, a2); a3 = fmaf(w0, f.y, a3);
        f = __builtin_amdgcn_cvt_pk_f32_fp8(q0.y, false); a4 = fmaf(w0, f.x, a4); a5 = fmaf(w0, f.y, a5);
        f = __builtin_amdgcn_cvt_pk_f32_fp8(q0.y, true);  a6 = fmaf(w0, f.x, a6); a7 = fmaf(w0, f.y, a7);
        f = __builtin_amdgcn_cvt_pk_f32_fp8(q1.x, false); a0 = fmaf(w1, f.x, a0); a1 = fmaf(w1, f.y, a1);
        f = __builtin_amdgcn_cvt_pk_f32_fp8(q1.x, true);  a2 = fmaf(w1, f.x, a2); a3 = fmaf(w1, f.y, a3);
        f = __builtin_amdgcn_cvt_pk_f32_fp8(q1.y, false); a4 = fmaf(w1, f.x, a4); a5 = fmaf(w1, f.y, a5);
        f = __builtin_amdgcn_cvt_pk_f32_fp8(q1.y, true);  a6 = fmaf(w1, f.x, a6); a7 = fmaf(w1, f.y, a7);
    }
    if (e < sp.y) {
        unsigned p = sorted[e];
        uint2 q = *(const uint2*)(t2 + (p & 0xFFFF) * 64 + fli * 8);
        float w = edge_w(p);
        f32x2 f;
        f = __builtin_amdgcn_cvt_pk_f32_fp8(q.x, false); a0 = fmaf(w, f.x, a0); a1 = fmaf(w, f.y, a1);
        f = __builtin_amdgcn_cvt_pk_f32_fp8(q.x, true);  a2 = fmaf(w, f.x, a2); a3 = fmaf(w, f.y, a3);
        f = __builtin_amdgcn_cvt_pk_f32_fp8(q.y, false); a4 = fmaf(w, f.x, a4); a5 = fmaf(w, f.y, a5);
        f = __builtin_amdgcn_cvt_pk_f32_fp8(q.y, true);  a6 = fmaf(w, f.x, a6); a7 = fmaf(w, f.y, a7);
    }
#pragma unroll
    for (int off = 8; off < 64; off <<= 1) {
        a0 += __shfl_xor(a0, off); a1 += __shfl_xor(a1, off);
        a2 += __shfl_xor(a2, off); a3 += __shfl_xor(a3, off);
        a4 += __shfl_xor(a4, off); a5 += __shfl_xor(a5, off);
        a6 += __shfl_xor(a6, off); a7 += __shfl_xor(a7, off);
    }
    float4 bA = *(const float4*)(b2 + fli * 8);
    float4 bB = *(const float4*)(b2 + fli * 8 + 4);
    float4 wA = *(const float4*)(W3 + fli * 8);
    float4 wB = *(const float4*)(W3 + fli * 8 + 4);
    float h = fmaxf(a0 + bA.x, 0.f) * wA.x + fmaxf(a1 + bA.y, 0.f) * wA.y +
              fmaxf(a2 + bA.z, 0.f) * wA.z + fmaxf(a3 + bA.w, 0.f) * wA.w +
              fmaxf(a4 + bB.x, 0.f) * wB.x + fmaxf(a5 + bB.y, 0.f) * wB.y +
              fmaxf(a6 + bB.z, 0.f) * wB.z + fmaxf(a7 + bB.w, 0.f) * wB.w;
#pragma unroll
    for (int off = 1; off < 8; off <<= 1) h += __shfl_xor(h, off);
    if (lane == 0) t3[node] = h;
}

// ====== Layer 3: gather scalar t3, 8 lanes/node (wave per 8 nodes) ======
__global__ void gather3(const int2* __restrict__ rowspan, const unsigned* __restrict__ sorted,
                        const float* __restrict__ t3, const float* __restrict__ b3,
                        float* __restrict__ out) {
    int gtid = blockIdx.x * blockDim.x + threadIdx.x;
    int wid = gtid >> 6;
    int lane = threadIdx.x & 63;
    int sub = lane >> 3;
    int sl  = lane & 7;
    int node = wid * 8 + sub;
    if (node >= N_NODES) return;
    int2 sp = rowspan[node];
    float acc = 0.f;
    for (int e = sp.x + sl; e < sp.y; e += 8) {
        unsigned p = sorted[e];
        acc = fmaf(edge_w(p), t3[p & 0xFFFF], acc);
    }
#pragma unroll
    for (int off = 1; off < 8; off <<= 1) acc += __shfl_xor(acc, off);
    if (sl == 0) out[node] = acc + b3[0];
}

extern "C" void kernel_launch(void* const* d_in, const int* in_sizes, int n_in,
                              void* d_out, int out_size, void* d_ws, size_t ws_size,
                              hipStream_t stream) {
    const float* x  = (const float*)d_in[0];
    const int*   ei = (const int*)d_in[1];     // [2, E]
    const float* ew = (const float*)d_in[2];
    const float* W1 = (const float*)d_in[3];
    const float* b1 = (const float*)d_in[4];
    const float* W2 = (const float*)d_in[5];
    const float* b2 = (const float*)d_in[6];
    const float* W3 = (const float*)d_in[7];
    const float* b3 = (const float*)d_in[8];
    float* out = (float*)d_out;

    const int* src = ei;
    const int* dst = ei + N_EDGES;

    // workspace layout
    char* p = (char*)d_ws;
    int*  bcur    = (int*)p;            p += NBKT * sizeof(int);
    p = (char*)(((uintptr_t)p + 15) & ~(uintptr_t)15);
    int2* rowspan = (int2*)p;           p += N_NODES * sizeof(int2);              // 400 KB
    uint2* brec   = (uint2*)p;          p += (long)NBKT * CAP * sizeof(uint2);    // 9.6 MB
    unsigned* sorted = (unsigned*)p;    p += (long)NBKT * CAP * sizeof(unsigned); // 4.6 MB
    unsigned char* t2 = (unsigned char*)p; p += 64L * N_NODES;                    // 3.2 MB (fp8)
    float* t3     = (float*)p;          p += N_NODES * sizeof(float);

    hipMemsetAsync(bcur, 0, NBKT * sizeof(int), stream);

    // CSR build pass 1: binning with LDS reorder -> coalesced uint2 scatter
    bin_edges<<<NBKT, BIN_THREADS, 0, stream>>>(src, dst, ew, bcur, brec);

    // Fused pass 2: reg-held bucket sort + layer-1 aggregation + MFMA dense 128->64 -> t2 fp8
    sort_l1<<<NBKT, SL_THREADS, 0, stream>>>(bcur, brec, x, W1, b1, W2, sorted, rowspan, t2);

    // Layer 2 gather + fused layer-3 projection
    gather2_dot3<<<(N_NODES * 64 + 255) / 256, 256, 0, stream>>>(rowspan, sorted, t2, b2, W3, t3);

    // Layer 3 (8 lanes/node)
    gather3<<<((N_NODES + 7) / 8 * 64 + 255) / 256, 256, 0, stream>>>(rowspan, sorted, t3, b3, out);
}